// Round 4
// baseline (9098.840 us; speedup 1.0000x reference)
//
#include <hip/hip_runtime.h>
#include <float.h>

#define DIM     64
#define NCODES  65536
#define KC      8
#define NQ      8192        // B*S = 4*2048

#define QPB     32          // queries per block (scan)
#define TC      256         // codes per tile (scan)
#define SLICES  4
#define SLICE_N (NCODES / SLICES)   // 16384
#define KCAND   16          // candidates kept per (query, slice)

// ---------------- kernel 1: c2[n] = sum_i codebook[n][i]^2 (fp32) ----------
__global__ __launch_bounds__(256) void k_c2(const float* __restrict__ cb,
                                            float* __restrict__ c2) {
    int n = blockIdx.x * 256 + threadIdx.x;
    const float4* row = (const float4*)(cb + (size_t)n * DIM);
    float s = 0.f;
#pragma unroll
    for (int i = 0; i < 16; ++i) {
        float4 v = row[i];
        s = fmaf(v.x, v.x, s); s = fmaf(v.y, v.y, s);
        s = fmaf(v.z, v.z, s); s = fmaf(v.w, v.w, s);
    }
    c2[n] = s;
}

// ---------------- kernel 2: fp32 scan, keep top-16 per (query, slice) ------
// Screening only: exact ordering is decided in k_final. Top-16-per-slice gives
// an 8-rank safety margin over the needed global top-8 — far beyond any fp32
// rounding discrepancy (~1e-5) vs order-statistic gaps.
__global__ __launch_bounds__(256) void k_scan(const float* __restrict__ x,
                                              const float* __restrict__ cb,
                                              const float* __restrict__ c2,
                                              int* __restrict__ cand) {
    __shared__ float s_scores[QPB][TC];     // 32 KB
    __shared__ float s_cs[QPB][KCAND];      // 2 KB
    __shared__ int   s_ci[QPB][KCAND];      // 2 KB
    __shared__ float s_thr[QPB];

    const int tid  = threadIdx.x;
    const int qg   = blockIdx.x >> 2;     // 0..255
    const int sl   = blockIdx.x & 3;      // 0..3
    const int q0   = qg * QPB;
    const int lane = tid & 63;
    const int wv   = tid >> 6;

    for (int i = tid; i < QPB * KCAND; i += 256) {
        ((float*)s_cs)[i] = -FLT_MAX;
        ((int*)s_ci)[i]   = 0;
    }
    if (tid < QPB) s_thr[tid] = -FLT_MAX;
    __syncthreads();

    const int base = sl * SLICE_N;
    for (int tile = 0; tile < SLICE_N / TC; ++tile) {
        const int code0 = base + tile * TC;
        const int code  = code0 + tid;

        // ---- scoring: acc[q] = dot(x[q0+q], cb[code]) ----
        float acc[QPB];
#pragma unroll
        for (int q = 0; q < QPB; ++q) acc[q] = 0.f;
        const float4* crow = (const float4*)(cb + (size_t)code * DIM);
#pragma unroll
        for (int ic = 0; ic < 16; ++ic) {
            const float4 v = crow[ic];
#pragma unroll
            for (int q = 0; q < QPB; ++q) {
                // wave-uniform address -> scalar loads
                const float4 xv = *(const float4*)(x + ((size_t)(q0 + q) << 6) + (ic << 2));
                acc[q] = fmaf(v.x, xv.x, acc[q]);
                acc[q] = fmaf(v.y, xv.y, acc[q]);
                acc[q] = fmaf(v.z, xv.z, acc[q]);
                acc[q] = fmaf(v.w, xv.w, acc[q]);
            }
        }
        const float c2v = c2[code];
#pragma unroll
        for (int q = 0; q < QPB; ++q)
            s_scores[q][tid] = fmaf(2.f, acc[q], -c2v);
        __syncthreads();

        // ---- selection: wave wv owns queries wv*8 .. wv*8+7 ----
        for (int qi = 0; qi < 8; ++qi) {
            const int q = wv * 8 + qi;
            const float4 sv = *(const float4*)&s_scores[q][lane * 4];
            const float m = fmaxf(fmaxf(sv.x, sv.y), fmaxf(sv.z, sv.w));
            unsigned long long mk = __ballot(m > s_thr[q]);
            while (mk) {
                const int leader = __ffsll(mk) - 1;
                if (lane == leader) {
                    volatile float* vcs  = &s_cs[q][0];
                    volatile float* vthr = &s_thr[q];
                    const float se[4] = {sv.x, sv.y, sv.z, sv.w};
#pragma unroll
                    for (int j = 0; j < 4; ++j) {
                        const float s = se[j];
                        if (s > *vthr) {             // fresh (volatile) threshold
                            int mi = 0; float mn = vcs[0];
#pragma unroll
                            for (int k = 1; k < KCAND; ++k) {
                                const float ck = vcs[k];
                                if (ck < mn) { mn = ck; mi = k; }
                            }
                            vcs[mi] = s;
                            s_ci[q][mi] = code0 + lane * 4 + j;
                            float nm = vcs[0];
#pragma unroll
                            for (int k = 1; k < KCAND; ++k) nm = fminf(nm, vcs[k]);
                            *vthr = nm;
                        }
                    }
                }
                mk &= mk - 1;
            }
        }
        __syncthreads();
    }

    // ---- write candidate ids: cand[q_global][64], slice sl owns cols 16*sl.. ----
    for (int i = tid; i < QPB * KCAND; i += 256) {
        const int q = i >> 4, k = i & 15;
        cand[(size_t)(q0 + q) * 64 + sl * KCAND + k] = s_ci[q][k];
    }
}

// ---- numpy pairwise_sum (n=64 base case): 8 accumulators stride 8, combined
//      ((r0+r1)+(r2+r3)) + ((r4+r5)+(r6+r7)); mul/add NOT contracted. --------
__device__ __forceinline__ float np_pairwise_sq64(const float* __restrict__ p) {
    float r[8];
#pragma unroll
    for (int j = 0; j < 8; ++j) r[j] = __fmul_rn(p[j], p[j]);
#pragma unroll
    for (int k = 1; k < 8; ++k)
#pragma unroll
        for (int j = 0; j < 8; ++j)
            r[j] = __fadd_rn(r[j], __fmul_rn(p[8 * k + j], p[8 * k + j]));
    const float t01 = __fadd_rn(r[0], r[1]);
    const float t23 = __fadd_rn(r[2], r[3]);
    const float t45 = __fadd_rn(r[4], r[5]);
    const float t67 = __fadd_rn(r[6], r[7]);
    return __fadd_rn(__fadd_rn(t01, t23), __fadd_rn(t45, t67));
}

// ---------------- kernel 3: f32-emulated rescore of 64 candidates ----------
// Reproduce the reference's float32 score arithmetic:
//   xc  = sequential FMA over d=0..63 (one-accumulator GEMM microkernel order)
//   x2  = numpy pairwise sum of x*x   (8-acc base case)
//   c2  = numpy pairwise sum of c*c
//   key = ((2*xc - x2) - c2), stepwise f32 rounding
// then top-8 by (key desc, index asc) — lax.top_k tie semantics.
// Ids written as FLOAT32 VALUES (harness reads whole d_out as f32).
__global__ __launch_bounds__(256) void k_final(const float* __restrict__ x,
                                               const float* __restrict__ cb,
                                               const int* __restrict__ cand,
                                               float* __restrict__ out0,
                                               float* __restrict__ out1) {
    const int lane = threadIdx.x & 63;
    const int q = blockIdx.x * 4 + (threadIdx.x >> 6);
    const float* xr = x + ((size_t)q << 6);

    const float x2e = np_pairwise_sq64(xr);

    const int id = cand[(size_t)q * 64 + lane];
    const float* cr = cb + (size_t)id * DIM;

    float xc = 0.f;
#pragma unroll
    for (int d = 0; d < DIM; ++d) xc = __builtin_fmaf(cr[d], xr[d], xc);

    const float c2e = np_pairwise_sq64(cr);

    float v = __fsub_rn(__fsub_rn(__fmul_rn(2.0f, xc), x2e), c2e);

    const int myid = id;
    double accd = 0.0;

#pragma unroll
    for (int rep = 0; rep < KC; ++rep) {
        float bv = v; int bi = myid;
#pragma unroll
        for (int off = 32; off; off >>= 1) {
            const float ov = __shfl_xor(bv, off, 64);
            const int   oi = __shfl_xor(bi, off, 64);
            if (ov > bv || (ov == bv && oi < bi)) { bv = ov; bi = oi; }
        }
        if (lane == 0) out1[q * KC + rep] = (float)bi;   // ids as float32 values
        accd += (double)cb[(size_t)bi * DIM + lane];     // lane = dim
        if (myid == bi) v = -FLT_MAX;                    // evict winner
    }
    out0[(size_t)q * DIM + lane] = (float)(accd * 0.125);
}

// ---------------------------------------------------------------------------
extern "C" void kernel_launch(void* const* d_in, const int* in_sizes, int n_in,
                              void* d_out, int out_size, void* d_ws, size_t ws_size,
                              hipStream_t stream) {
    const float* x  = (const float*)d_in[0];   // [8192][64]
    const float* cb = (const float*)d_in[1];   // [65536][64]

    float* c2   = (float*)d_ws;                          // 256 KB
    int*   cand = (int*)((char*)d_ws + NCODES * 4);      // 2 MB

    float* out0 = (float*)d_out;                            // [8192][64] f32
    float* out1 = (float*)d_out + (size_t)NQ * DIM;         // [8192][8] ids-as-f32

    k_c2   <<<NCODES / 256, 256, 0, stream>>>(cb, c2);
    k_scan <<<(NQ / QPB) * SLICES, 256, 0, stream>>>(x, cb, c2, cand);
    k_final<<<NQ / 4, 256, 0, stream>>>(x, cb, cand, out0, out1);
}

// Round 5
// 1259.565 us; speedup vs baseline: 7.2238x; 7.2238x over previous
//
#include <hip/hip_runtime.h>
#include <float.h>

#define DIM     64
#define NCODES  65536
#define KC      8
#define NQ      8192        // B*S
#define KROW    80          // padded bf16 row: 64 data + c2_hi + c2_lo + zeros (5 mfma k-steps)
#define KL      16          // candidates kept per lane

typedef __bf16 bf16x8 __attribute__((ext_vector_type(8)));
typedef float  f32x16 __attribute__((ext_vector_type(16)));
typedef unsigned short u16x8 __attribute__((ext_vector_type(8)));

static __device__ __forceinline__ unsigned short f2bf(float f) {
    unsigned u = __float_as_uint(f);
    u += 0x7FFFu + ((u >> 16) & 1u);
    return (unsigned short)(u >> 16);
}

// ---------------- kernel 1: c2[n] = sum_d cb[n][d]^2 (fp32, screening aid) --
__global__ __launch_bounds__(256) void k_c2(const float* __restrict__ cb,
                                            float* __restrict__ c2) {
    int n = blockIdx.x * 256 + threadIdx.x;
    const float4* row = (const float4*)(cb + (size_t)n * DIM);
    float s = 0.f;
#pragma unroll
    for (int i = 0; i < 16; ++i) {
        float4 v = row[i];
        s = fmaf(v.x, v.x, s); s = fmaf(v.y, v.y, s);
        s = fmaf(v.z, v.z, s); s = fmaf(v.w, v.w, s);
    }
    c2[n] = s;
}

// ---------------- kernel 2a: codebook -> augmented bf16 rows ---------------
// cbb[n][k] = bf16(2*cb[n][k]) for k<64; k=64: -bf16(c2); k=65: -bf16(residual)
__global__ __launch_bounds__(256) void k_conv_cb(const float* __restrict__ cb,
                                                 const float* __restrict__ c2,
                                                 unsigned short* __restrict__ cbb) {
    int n = blockIdx.x * 256 + threadIdx.x;
    const float4* src = (const float4*)(cb + (size_t)n * DIM);
    unsigned short* dst = cbb + (size_t)n * KROW;
#pragma unroll
    for (int c = 0; c < 8; ++c) {
        float4 f0 = src[2 * c], f1 = src[2 * c + 1];
        u16x8 o;
        o[0] = f2bf(2.f * f0.x); o[1] = f2bf(2.f * f0.y);
        o[2] = f2bf(2.f * f0.z); o[3] = f2bf(2.f * f0.w);
        o[4] = f2bf(2.f * f1.x); o[5] = f2bf(2.f * f1.y);
        o[6] = f2bf(2.f * f1.z); o[7] = f2bf(2.f * f1.w);
        *(u16x8*)(dst + c * 8) = o;
    }
    float c2f = c2[n];
    unsigned short hi = f2bf(c2f);
    float hif = __uint_as_float(((unsigned)hi) << 16);
    unsigned short lo = f2bf(c2f - hif);
    u16x8 p = { (unsigned short)(hi ^ 0x8000u), (unsigned short)(lo ^ 0x8000u),
                0, 0, 0, 0, 0, 0 };
    *(u16x8*)(dst + 64) = p;
    u16x8 z = {0, 0, 0, 0, 0, 0, 0, 0};
    *(u16x8*)(dst + 72) = z;
}

// ---------------- kernel 2b: x -> augmented bf16 rows ----------------------
// xb[q][k] = bf16(x[q][k]) for k<64; k=64,65: 1.0 (pairs with -c2_hi,-c2_lo)
__global__ __launch_bounds__(256) void k_conv_x(const float* __restrict__ x,
                                                unsigned short* __restrict__ xb) {
    int n = blockIdx.x * 256 + threadIdx.x;
    const float4* src = (const float4*)(x + (size_t)n * DIM);
    unsigned short* dst = xb + (size_t)n * KROW;
#pragma unroll
    for (int c = 0; c < 8; ++c) {
        float4 f0 = src[2 * c], f1 = src[2 * c + 1];
        u16x8 o;
        o[0] = f2bf(f0.x); o[1] = f2bf(f0.y); o[2] = f2bf(f0.z); o[3] = f2bf(f0.w);
        o[4] = f2bf(f1.x); o[5] = f2bf(f1.y); o[6] = f2bf(f1.z); o[7] = f2bf(f1.w);
        *(u16x8*)(dst + c * 8) = o;
    }
    u16x8 p = {0x3F80u, 0x3F80u, 0, 0, 0, 0, 0, 0};   // 1.0, 1.0
    *(u16x8*)(dst + 64) = p;
    u16x8 z = {0, 0, 0, 0, 0, 0, 0, 0};
    *(u16x8*)(dst + 72) = z;
}

// ---------------- kernel 3: MFMA screening scan ----------------------------
// grid 256 = (qg 0..127) x (h 0..1). block = 4 waves: (qt 0..1) x (cw 0..1).
// Wave: A=codes (M), B=queries (N) -> mfma_f32_32x32x16_bf16, 5 k-steps.
// C/D layout (HW-verified): col=lane&31 (query), row=(reg&3)+8*(reg>>2)+4*(lane>>5).
// Each lane keeps top-16 (score,id) of the 16 code-rows it sees per tile.
__global__ __launch_bounds__(256) void k_mscan(const unsigned short* __restrict__ cbb_,
                                               const unsigned short* __restrict__ xb_,
                                               int* __restrict__ cand) {
    const __bf16* cbv = (const __bf16*)cbb_;
    const __bf16* xbv = (const __bf16*)xb_;
    const int tid = threadIdx.x, lane = tid & 63, wv = tid >> 6;
    const int laneh = lane >> 5;
    const int qg = blockIdx.x >> 1, h = blockIdx.x & 1;
    const int qt = wv >> 1, cw = wv & 1;
    const int q = qg * 64 + qt * 32 + (lane & 31);
    const int cbase = h * 32768 + cw * 16384;

    bf16x8 bfr[5];
    {
        const __bf16* bp = xbv + (size_t)q * KROW + laneh * 8;
#pragma unroll
        for (int s = 0; s < 5; ++s) bfr[s] = *(const bf16x8*)(bp + s * 16);
    }

    float sc[KL]; int idt[KL];
#pragma unroll
    for (int k = 0; k < KL; ++k) { sc[k] = -FLT_MAX; idt[k] = 0; }
    float thr = -FLT_MAX;

    const __bf16* ap = cbv + (size_t)(cbase + (lane & 31)) * KROW + laneh * 8;

    for (int it = 0; it < 512; ++it) {
        f32x16 acc = {0,0,0,0, 0,0,0,0, 0,0,0,0, 0,0,0,0};
#pragma unroll
        for (int s = 0; s < 5; ++s)
            acc = __builtin_amdgcn_mfma_f32_32x32x16_bf16(
                      *(const bf16x8*)(ap + s * 16), bfr[s], acc, 0, 0, 0);

        float m0 = fmaxf(fmaxf(acc[0],  acc[1]),  fmaxf(acc[2],  acc[3]));
        float m1 = fmaxf(fmaxf(acc[4],  acc[5]),  fmaxf(acc[6],  acc[7]));
        float m2 = fmaxf(fmaxf(acc[8],  acc[9]),  fmaxf(acc[10], acc[11]));
        float m3 = fmaxf(fmaxf(acc[12], acc[13]), fmaxf(acc[14], acc[15]));
        float vmax = fmaxf(fmaxf(m0, m1), fmaxf(m2, m3));

        if (vmax > thr) {
            const int code0 = cbase + it * 32;
#pragma unroll
            for (int k = 0; k < 16; ++k) {
                float v = acc[k];
                if (v > thr) {
                    const int cid = code0 + ((k & 3) + 8 * (k >> 2) + 4 * laneh);
                    float mn = sc[0];
#pragma unroll
                    for (int j = 1; j < KL; ++j) mn = fminf(mn, sc[j]);
                    bool done = false;
#pragma unroll
                    for (int j = 0; j < KL; ++j) {
                        bool r = (!done) && (sc[j] == mn);
                        if (r) { sc[j] = v; idt[j] = cid; }
                        done = done || r;
                    }
                    float nt = sc[0];
#pragma unroll
                    for (int j = 1; j < KL; ++j) nt = fminf(nt, sc[j]);
                    thr = nt;
                }
            }
        }
        ap += 32 * KROW;
    }

    int* cp = cand + (size_t)q * 128 + ((size_t)((h * 2 + cw) * 2 + laneh)) * KL;
#pragma unroll
    for (int k = 0; k < KL; ++k) cp[k] = idt[k];
}

// ---- numpy pairwise_sum (n=64 base case), mul/add NOT contracted ----------
__device__ __forceinline__ float np_pairwise_sq64(const float* __restrict__ p) {
    float r[8];
#pragma unroll
    for (int j = 0; j < 8; ++j) r[j] = __fmul_rn(p[j], p[j]);
#pragma unroll
    for (int k = 1; k < 8; ++k)
#pragma unroll
        for (int j = 0; j < 8; ++j)
            r[j] = __fadd_rn(r[j], __fmul_rn(p[8 * k + j], p[8 * k + j]));
    const float t01 = __fadd_rn(r[0], r[1]);
    const float t23 = __fadd_rn(r[2], r[3]);
    const float t45 = __fadd_rn(r[4], r[5]);
    const float t67 = __fadd_rn(r[6], r[7]);
    return __fadd_rn(__fadd_rn(t01, t23), __fadd_rn(t45, t67));
}

// reference-f32 score key: ((2*xc - x2) - c2), xc = sequential fma chain
__device__ __forceinline__ float score_key(const float* __restrict__ xr,
                                           const float* __restrict__ cr,
                                           float x2e) {
    float xc = 0.f;
#pragma unroll
    for (int d = 0; d < DIM; ++d) xc = __builtin_fmaf(cr[d], xr[d], xc);
    const float c2e = np_pairwise_sq64(cr);
    return __fsub_rn(__fsub_rn(__fmul_rn(2.0f, xc), x2e), c2e);
}

// ---------------- kernel 4: exact-f32 rescore of 128 candidates ------------
// one wave per query; lane handles candidates lane and lane+64.
// ids written as FLOAT32 VALUES (harness reads whole d_out as f32).
__global__ __launch_bounds__(256) void k_final(const float* __restrict__ x,
                                               const float* __restrict__ cb,
                                               const int* __restrict__ cand,
                                               float* __restrict__ out0,
                                               float* __restrict__ out1) {
    const int lane = threadIdx.x & 63;
    const int q = blockIdx.x * 4 + (threadIdx.x >> 6);
    const float* xr = x + ((size_t)q << 6);

    const float x2e = np_pairwise_sq64(xr);

    int ida = cand[(size_t)q * 128 + lane];
    int idb = cand[(size_t)q * 128 + 64 + lane];
    float va = score_key(xr, cb + (size_t)ida * DIM, x2e);
    float vb = score_key(xr, cb + (size_t)idb * DIM, x2e);

    double accd = 0.0;
#pragma unroll
    for (int rep = 0; rep < KC; ++rep) {
        float bv; int bi;
        if (va > vb || (va == vb && ida < idb)) { bv = va; bi = ida; }
        else                                    { bv = vb; bi = idb; }
#pragma unroll
        for (int off = 32; off; off >>= 1) {
            const float ov = __shfl_xor(bv, off, 64);
            const int   oi = __shfl_xor(bi, off, 64);
            if (ov > bv || (ov == bv && oi < bi)) { bv = ov; bi = oi; }
        }
        if (lane == 0) out1[q * KC + rep] = (float)bi;   // rank-ordered ids
        accd += (double)cb[(size_t)bi * DIM + lane];     // lane = dim
        if (ida == bi) va = -FLT_MAX;                    // evict winner
        if (idb == bi) vb = -FLT_MAX;
    }
    out0[(size_t)q * DIM + lane] = (float)(accd * 0.125);
}

// ---------------------------------------------------------------------------
extern "C" void kernel_launch(void* const* d_in, const int* in_sizes, int n_in,
                              void* d_out, int out_size, void* d_ws, size_t ws_size,
                              hipStream_t stream) {
    const float* x  = (const float*)d_in[0];   // [8192][64]
    const float* cb = (const float*)d_in[1];   // [65536][64]

    char* ws = (char*)d_ws;
    float*          c2f  = (float*)ws;                                   // 256 KB
    int*            cand = (int*)(ws + (size_t)NCODES * 4);              // 4 MB
    unsigned short* cbb  = (unsigned short*)(ws + (size_t)NCODES * 4
                                                + (size_t)NQ * 128 * 4); // 10 MB
    unsigned short* xb   = (unsigned short*)((char*)cbb
                                                + (size_t)NCODES * KROW * 2); // 1.25 MB

    float* out0 = (float*)d_out;                       // [8192][64] f32
    float* out1 = (float*)d_out + (size_t)NQ * DIM;    // [8192][8] ids-as-f32

    k_c2     <<<NCODES / 256, 256, 0, stream>>>(cb, c2f);
    k_conv_cb<<<NCODES / 256, 256, 0, stream>>>(cb, c2f, cbb);
    k_conv_x <<<NQ / 256,     256, 0, stream>>>(x, xb);
    k_mscan  <<<256,          256, 0, stream>>>(cbb, xb, cand);
    k_final  <<<NQ / 4,       256, 0, stream>>>(x, cb, cand, out0, out1);
}

// Round 6
// 1123.556 us; speedup vs baseline: 8.0983x; 1.1211x over previous
//
#include <hip/hip_runtime.h>
#include <float.h>

#define DIM     64
#define NCODES  65536
#define KC      8
#define NQ      8192        // B*S
#define KROW    80          // padded bf16 row: 64 data + c2_hi + c2_lo + zeros (5 mfma k-steps)
#define KL      16          // candidates kept per lane-view (8 rank + 8 noise slack)
#define CS      8           // code splits (views/query = CS*2)
#define CHUNK   (NCODES/CS) // 8192 codes per wave-scan
#define NITER   (CHUNK/32)  // 256 iterations

typedef __bf16 bf16x8 __attribute__((ext_vector_type(8)));
typedef float  f32x16 __attribute__((ext_vector_type(16)));
typedef unsigned short u16x8 __attribute__((ext_vector_type(8)));

static __device__ __forceinline__ unsigned short f2bf(float f) {
    unsigned u = __float_as_uint(f);
    u += 0x7FFFu + ((u >> 16) & 1u);
    return (unsigned short)(u >> 16);
}

// ---------------- kernel 1: c2[n] = sum_d cb[n][d]^2 (fp32, screening aid) --
__global__ __launch_bounds__(256) void k_c2(const float* __restrict__ cb,
                                            float* __restrict__ c2) {
    int n = blockIdx.x * 256 + threadIdx.x;
    const float4* row = (const float4*)(cb + (size_t)n * DIM);
    float s = 0.f;
#pragma unroll
    for (int i = 0; i < 16; ++i) {
        float4 v = row[i];
        s = fmaf(v.x, v.x, s); s = fmaf(v.y, v.y, s);
        s = fmaf(v.z, v.z, s); s = fmaf(v.w, v.w, s);
    }
    c2[n] = s;
}

// ---------------- kernel 2a: codebook -> augmented bf16 rows ---------------
__global__ __launch_bounds__(256) void k_conv_cb(const float* __restrict__ cb,
                                                 const float* __restrict__ c2,
                                                 unsigned short* __restrict__ cbb) {
    int n = blockIdx.x * 256 + threadIdx.x;
    const float4* src = (const float4*)(cb + (size_t)n * DIM);
    unsigned short* dst = cbb + (size_t)n * KROW;
#pragma unroll
    for (int c = 0; c < 8; ++c) {
        float4 f0 = src[2 * c], f1 = src[2 * c + 1];
        u16x8 o;
        o[0] = f2bf(2.f * f0.x); o[1] = f2bf(2.f * f0.y);
        o[2] = f2bf(2.f * f0.z); o[3] = f2bf(2.f * f0.w);
        o[4] = f2bf(2.f * f1.x); o[5] = f2bf(2.f * f1.y);
        o[6] = f2bf(2.f * f1.z); o[7] = f2bf(2.f * f1.w);
        *(u16x8*)(dst + c * 8) = o;
    }
    float c2f = c2[n];
    unsigned short hi = f2bf(c2f);
    float hif = __uint_as_float(((unsigned)hi) << 16);
    unsigned short lo = f2bf(c2f - hif);
    u16x8 p = { (unsigned short)(hi ^ 0x8000u), (unsigned short)(lo ^ 0x8000u),
                0, 0, 0, 0, 0, 0 };
    *(u16x8*)(dst + 64) = p;
    u16x8 z = {0, 0, 0, 0, 0, 0, 0, 0};
    *(u16x8*)(dst + 72) = z;
}

// ---------------- kernel 2b: x -> augmented bf16 rows ----------------------
__global__ __launch_bounds__(256) void k_conv_x(const float* __restrict__ x,
                                                unsigned short* __restrict__ xb) {
    int n = blockIdx.x * 256 + threadIdx.x;
    const float4* src = (const float4*)(x + (size_t)n * DIM);
    unsigned short* dst = xb + (size_t)n * KROW;
#pragma unroll
    for (int c = 0; c < 8; ++c) {
        float4 f0 = src[2 * c], f1 = src[2 * c + 1];
        u16x8 o;
        o[0] = f2bf(f0.x); o[1] = f2bf(f0.y); o[2] = f2bf(f0.z); o[3] = f2bf(f0.w);
        o[4] = f2bf(f1.x); o[5] = f2bf(f1.y); o[6] = f2bf(f1.z); o[7] = f2bf(f1.w);
        *(u16x8*)(dst + c * 8) = o;
    }
    u16x8 p = {0x3F80u, 0x3F80u, 0, 0, 0, 0, 0, 0};   // 1.0, 1.0
    *(u16x8*)(dst + 64) = p;
    u16x8 z = {0, 0, 0, 0, 0, 0, 0, 0};
    *(u16x8*)(dst + 72) = z;
}

// ---- per-tile selection: lane keeps top-KL of the 16 code-rows it sees ----
__device__ __forceinline__ void sel16(const f32x16& acc, int code0, int laneh,
                                      float (&sc)[KL], int (&idt)[KL], float& thr) {
    float m0 = fmaxf(fmaxf(acc[0],  acc[1]),  fmaxf(acc[2],  acc[3]));
    float m1 = fmaxf(fmaxf(acc[4],  acc[5]),  fmaxf(acc[6],  acc[7]));
    float m2 = fmaxf(fmaxf(acc[8],  acc[9]),  fmaxf(acc[10], acc[11]));
    float m3 = fmaxf(fmaxf(acc[12], acc[13]), fmaxf(acc[14], acc[15]));
    float vmax = fmaxf(fmaxf(m0, m1), fmaxf(m2, m3));
    if (vmax > thr) {
#pragma unroll
        for (int k = 0; k < 16; ++k) {
            float v = acc[k];
            if (v > thr) {
                const int cid = code0 + ((k & 3) + 8 * (k >> 2) + 4 * laneh);
                float mn = sc[0];
#pragma unroll
                for (int j = 1; j < KL; ++j) mn = fminf(mn, sc[j]);
                bool done = false;
#pragma unroll
                for (int j = 0; j < KL; ++j) {
                    bool r = (!done) && (sc[j] == mn);
                    if (r) { sc[j] = v; idt[j] = cid; }
                    done = done || r;
                }
                float nt = sc[0];
#pragma unroll
                for (int j = 1; j < KL; ++j) nt = fminf(nt, sc[j]);
                thr = nt;
            }
        }
    }
}

// ---------------- kernel 3: MFMA screening scan ----------------------------
// grid 512 = (qg 0..63) x (cs 0..7). block = 4 waves (qt 0..3), wave = 32 q.
// Wave scans CHUNK=8192 codes (256 iters x 32 codes), depth-2 prefetch.
// C/D layout (HW-verified): col=lane&31 (query), row=(reg&3)+8*(reg>>2)+4*laneh.
__global__ __launch_bounds__(256) void k_mscan(const unsigned short* __restrict__ cbb_,
                                               const unsigned short* __restrict__ xb_,
                                               unsigned short* __restrict__ cand) {
    const __bf16* cbv = (const __bf16*)cbb_;
    const __bf16* xbv = (const __bf16*)xb_;
    const int tid = threadIdx.x, lane = tid & 63, wv = tid >> 6;
    const int laneh = lane >> 5;
    const int qg = blockIdx.x >> 3;       // 0..63
    const int cs = blockIdx.x & 7;        // 0..7
    const int q = qg * 128 + wv * 32 + (lane & 31);
    const int cbase = cs * CHUNK;

    bf16x8 bfr[5];
    {
        const __bf16* bp = xbv + (size_t)q * KROW + laneh * 8;
#pragma unroll
        for (int s = 0; s < 5; ++s) bfr[s] = *(const bf16x8*)(bp + s * 16);
    }

    float sc[KL]; int idt[KL];
#pragma unroll
    for (int k = 0; k < KL; ++k) { sc[k] = -FLT_MAX; idt[k] = 0; }
    float thr = -FLT_MAX;

    const __bf16* ap = cbv + (size_t)(cbase + (lane & 31)) * KROW + laneh * 8;
    bf16x8 fA[5], fB[5];
#pragma unroll
    for (int s = 0; s < 5; ++s) fA[s] = *(const bf16x8*)(ap + s * 16);
#pragma unroll
    for (int s = 0; s < 5; ++s) fB[s] = *(const bf16x8*)(ap + 32 * KROW + s * 16);
    ap += 64 * KROW;    // points at tile it+2

    for (int it = 0; it < NITER; it += 2) {
        f32x16 acc = {0,0,0,0, 0,0,0,0, 0,0,0,0, 0,0,0,0};
#pragma unroll
        for (int s = 0; s < 5; ++s)
            acc = __builtin_amdgcn_mfma_f32_32x32x16_bf16(fA[s], bfr[s], acc, 0, 0, 0);
#pragma unroll
        for (int s = 0; s < 5; ++s) fA[s] = *(const bf16x8*)(ap + s * 16);  // prefetch it+2
        sel16(acc, cbase + it * 32, laneh, sc, idt, thr);

        f32x16 acc2 = {0,0,0,0, 0,0,0,0, 0,0,0,0, 0,0,0,0};
#pragma unroll
        for (int s = 0; s < 5; ++s)
            acc2 = __builtin_amdgcn_mfma_f32_32x32x16_bf16(fB[s], bfr[s], acc2, 0, 0, 0);
#pragma unroll
        for (int s = 0; s < 5; ++s) fB[s] = *(const bf16x8*)(ap + 32 * KROW + s * 16); // it+3
        ap += 64 * KROW;
        sel16(acc2, cbase + (it + 1) * 32, laneh, sc, idt, thr);
    }

    unsigned short* cp = cand + (size_t)q * 256 + (size_t)(cs * 2 + laneh) * KL;
#pragma unroll
    for (int k = 0; k < KL; ++k) cp[k] = (unsigned short)idt[k];
}

// ---- numpy pairwise_sum (n=64 base case), mul/add NOT contracted ----------
__device__ __forceinline__ float np_pairwise_sq64(const float* __restrict__ p) {
    float r[8];
#pragma unroll
    for (int j = 0; j < 8; ++j) r[j] = __fmul_rn(p[j], p[j]);
#pragma unroll
    for (int k = 1; k < 8; ++k)
#pragma unroll
        for (int j = 0; j < 8; ++j)
            r[j] = __fadd_rn(r[j], __fmul_rn(p[8 * k + j], p[8 * k + j]));
    const float t01 = __fadd_rn(r[0], r[1]);
    const float t23 = __fadd_rn(r[2], r[3]);
    const float t45 = __fadd_rn(r[4], r[5]);
    const float t67 = __fadd_rn(r[6], r[7]);
    return __fadd_rn(__fadd_rn(t01, t23), __fadd_rn(t45, t67));
}

// reference-f32 score key: ((2*xc - x2) - c2), xc = sequential fma chain
__device__ __forceinline__ float score_key(const float* __restrict__ xr,
                                           const float* __restrict__ cr,
                                           float x2e) {
    float xc = 0.f;
#pragma unroll
    for (int d = 0; d < DIM; ++d) xc = __builtin_fmaf(cr[d], xr[d], xc);
    const float c2e = np_pairwise_sq64(cr);
    return __fsub_rn(__fsub_rn(__fmul_rn(2.0f, xc), x2e), c2e);
}

// ---------------- kernel 4: exact-f32 rescore of 256 candidates ------------
// one wave per query; lane handles candidates lane + {0,64,128,192}.
// ids written as FLOAT32 VALUES (harness reads whole d_out as f32).
__global__ __launch_bounds__(256) void k_final(const float* __restrict__ x,
                                               const float* __restrict__ cb,
                                               const unsigned short* __restrict__ cand,
                                               float* __restrict__ out0,
                                               float* __restrict__ out1) {
    const int lane = threadIdx.x & 63;
    const int q = blockIdx.x * 4 + (threadIdx.x >> 6);
    const float* xr = x + ((size_t)q << 6);

    const float x2e = np_pairwise_sq64(xr);

    int id[4]; float v[4];
#pragma unroll
    for (int j = 0; j < 4; ++j) {
        id[j] = cand[(size_t)q * 256 + j * 64 + lane];
        v[j] = score_key(xr, cb + (size_t)id[j] * DIM, x2e);
    }

    double accd = 0.0;
#pragma unroll
    for (int rep = 0; rep < KC; ++rep) {
        float bv = v[0]; int bi = id[0];
#pragma unroll
        for (int j = 1; j < 4; ++j)
            if (v[j] > bv || (v[j] == bv && id[j] < bi)) { bv = v[j]; bi = id[j]; }
#pragma unroll
        for (int off = 32; off; off >>= 1) {
            const float ov = __shfl_xor(bv, off, 64);
            const int   oi = __shfl_xor(bi, off, 64);
            if (ov > bv || (ov == bv && oi < bi)) { bv = ov; bi = oi; }
        }
        if (lane == 0) out1[q * KC + rep] = (float)bi;   // rank-ordered ids
        accd += (double)cb[(size_t)bi * DIM + lane];     // lane = dim
#pragma unroll
        for (int j = 0; j < 4; ++j) if (id[j] == bi) v[j] = -FLT_MAX;
    }
    out0[(size_t)q * DIM + lane] = (float)(accd * 0.125);
}

// ---------------------------------------------------------------------------
extern "C" void kernel_launch(void* const* d_in, const int* in_sizes, int n_in,
                              void* d_out, int out_size, void* d_ws, size_t ws_size,
                              hipStream_t stream) {
    const float* x  = (const float*)d_in[0];   // [8192][64]
    const float* cb = (const float*)d_in[1];   // [65536][64]

    char* ws = (char*)d_ws;
    float*          c2f  = (float*)ws;                                    // 256 KB
    unsigned short* cand = (unsigned short*)(ws + (size_t)NCODES * 4);    // 4 MB
    unsigned short* cbb  = (unsigned short*)(ws + (size_t)NCODES * 4
                                                + (size_t)NQ * 256 * 2);  // 10.5 MB
    unsigned short* xb   = (unsigned short*)((char*)cbb
                                                + (size_t)NCODES * KROW * 2); // 1.31 MB

    float* out0 = (float*)d_out;                       // [8192][64] f32
    float* out1 = (float*)d_out + (size_t)NQ * DIM;    // [8192][8] ids-as-f32

    k_c2     <<<NCODES / 256, 256, 0, stream>>>(cb, c2f);
    k_conv_cb<<<NCODES / 256, 256, 0, stream>>>(cb, c2f, cbb);
    k_conv_x <<<NQ / 256,     256, 0, stream>>>(x, xb);
    k_mscan  <<<512,          256, 0, stream>>>(cbb, xb, cand);
    k_final  <<<NQ / 4,       256, 0, stream>>>(x, cb, cand, out0, out1);
}

// Round 7
// 334.266 us; speedup vs baseline: 27.2204x; 3.3613x over previous
//
#include <hip/hip_runtime.h>
#include <float.h>

#define DIM     64
#define NCODES  65536
#define KC      8
#define NQ      8192        // B*S
#define KROW    80          // padded bf16 row: 64 data + c2_hi + c2_lo + zeros (5 mfma k-steps)
#define CS      16          // code splits
#define CHUNK   (NCODES/CS) // 4096 codes per wave-scan
#define NITER   (CHUNK/32)  // 128 tiles
#define NVIEW   32          // CS * 2 lane-halves (disjoint code views per query)
#define CAP     20          // candidate slots per (query,view)
#define DELTA   1.5f        // collect margin: >= 2 * worst bf16-vs-exact score error

typedef __bf16 bf16x8 __attribute__((ext_vector_type(8)));
typedef float  f32x16 __attribute__((ext_vector_type(16)));
typedef unsigned short u16x8 __attribute__((ext_vector_type(8)));

static __device__ __forceinline__ unsigned short f2bf(float f) {
    unsigned u = __float_as_uint(f);
    u += 0x7FFFu + ((u >> 16) & 1u);
    return (unsigned short)(u >> 16);
}

#define RJ(j) (((j) & 3) + 8 * ((j) >> 2))   // C/D row for acc reg j (HW-verified)

// ---------------- kernel 1: codebook -> augmented bf16 rows (c2 inline) ----
// cbb[n][k] = bf16(2*cb[n][k]) k<64; k=64: -bf16hi(c2); k=65: -bf16lo(c2); pad 0
__global__ __launch_bounds__(256) void k_conv_cb(const float* __restrict__ cb,
                                                 unsigned short* __restrict__ cbb) {
    int n = blockIdx.x * 256 + threadIdx.x;
    const float4* src = (const float4*)(cb + (size_t)n * DIM);
    unsigned short* dst = cbb + (size_t)n * KROW;
    float s = 0.f;
#pragma unroll
    for (int c = 0; c < 8; ++c) {
        float4 f0 = src[2 * c], f1 = src[2 * c + 1];
        s = fmaf(f0.x, f0.x, s); s = fmaf(f0.y, f0.y, s);
        s = fmaf(f0.z, f0.z, s); s = fmaf(f0.w, f0.w, s);
        s = fmaf(f1.x, f1.x, s); s = fmaf(f1.y, f1.y, s);
        s = fmaf(f1.z, f1.z, s); s = fmaf(f1.w, f1.w, s);
        u16x8 o;
        o[0] = f2bf(2.f * f0.x); o[1] = f2bf(2.f * f0.y);
        o[2] = f2bf(2.f * f0.z); o[3] = f2bf(2.f * f0.w);
        o[4] = f2bf(2.f * f1.x); o[5] = f2bf(2.f * f1.y);
        o[6] = f2bf(2.f * f1.z); o[7] = f2bf(2.f * f1.w);
        *(u16x8*)(dst + c * 8) = o;
    }
    unsigned short hi = f2bf(s);
    float hif = __uint_as_float(((unsigned)hi) << 16);
    unsigned short lo = f2bf(s - hif);
    u16x8 p = { (unsigned short)(hi ^ 0x8000u), (unsigned short)(lo ^ 0x8000u),
                0, 0, 0, 0, 0, 0 };
    *(u16x8*)(dst + 64) = p;
    u16x8 z = {0, 0, 0, 0, 0, 0, 0, 0};
    *(u16x8*)(dst + 72) = z;
}

// ---------------- kernel 2: x -> augmented bf16 rows -----------------------
__global__ __launch_bounds__(256) void k_conv_x(const float* __restrict__ x,
                                                unsigned short* __restrict__ xb) {
    int n = blockIdx.x * 256 + threadIdx.x;
    const float4* src = (const float4*)(x + (size_t)n * DIM);
    unsigned short* dst = xb + (size_t)n * KROW;
#pragma unroll
    for (int c = 0; c < 8; ++c) {
        float4 f0 = src[2 * c], f1 = src[2 * c + 1];
        u16x8 o;
        o[0] = f2bf(f0.x); o[1] = f2bf(f0.y); o[2] = f2bf(f0.z); o[3] = f2bf(f0.w);
        o[4] = f2bf(f1.x); o[5] = f2bf(f1.y); o[6] = f2bf(f1.z); o[7] = f2bf(f1.w);
        *(u16x8*)(dst + c * 8) = o;
    }
    u16x8 p = {0x3F80u, 0x3F80u, 0, 0, 0, 0, 0, 0};   // 1.0, 1.0
    *(u16x8*)(dst + 64) = p;
    u16x8 z = {0, 0, 0, 0, 0, 0, 0, 0};
    *(u16x8*)(dst + 72) = z;
}

// branchless top-2 update over one tile's 16 scores (3 ops/elem)
__device__ __forceinline__ void upd2(const f32x16& acc, float& t1, float& t2) {
#pragma unroll
    for (int j = 0; j < 16; ++j) {
        const float v = acc[j];
        const float tmp = fminf(t1, v);
        t1 = fmaxf(t1, v);
        t2 = fmaxf(t2, tmp);
    }
}

// ---------------- kernel 3: scan #1 — per-view top-2 values ----------------
// grid 1024 = (qg 0..63) x (cs 0..15). block 4 waves (wv = query tile).
// Wave scans CHUNK=4096 codes, depth-2 prefetch. Lane = one query, one view.
__global__ __launch_bounds__(256) void k_scanA(const unsigned short* __restrict__ cbb_,
                                               const unsigned short* __restrict__ xb_,
                                               float* __restrict__ top2) {
    const __bf16* cbv = (const __bf16*)cbb_;
    const __bf16* xbv = (const __bf16*)xb_;
    const int tid = threadIdx.x, lane = tid & 63, wv = tid >> 6;
    const int laneh = lane >> 5;
    const int qg = blockIdx.x >> 4;     // 0..63
    const int cs = blockIdx.x & 15;     // 0..15
    const int q = qg * 128 + wv * 32 + (lane & 31);
    const int cbase = cs * CHUNK;

    bf16x8 bfr[5];
    {
        const __bf16* bp = xbv + (size_t)q * KROW + laneh * 8;
#pragma unroll
        for (int s = 0; s < 5; ++s) bfr[s] = *(const bf16x8*)(bp + s * 16);
    }

    float t1 = -FLT_MAX, t2 = -FLT_MAX;

    const __bf16* ap = cbv + (size_t)(cbase + (lane & 31)) * KROW + laneh * 8;
    bf16x8 fA[5], fB[5];
#pragma unroll
    for (int s = 0; s < 5; ++s) fA[s] = *(const bf16x8*)(ap + s * 16);
#pragma unroll
    for (int s = 0; s < 5; ++s) fB[s] = *(const bf16x8*)(ap + 32 * KROW + s * 16);
    ap += 64 * KROW;

    for (int it = 0; it < NITER; it += 2) {
        f32x16 acc = {0,0,0,0, 0,0,0,0, 0,0,0,0, 0,0,0,0};
#pragma unroll
        for (int s = 0; s < 5; ++s)
            acc = __builtin_amdgcn_mfma_f32_32x32x16_bf16(fA[s], bfr[s], acc, 0, 0, 0);
#pragma unroll
        for (int s = 0; s < 5; ++s) fA[s] = *(const bf16x8*)(ap + s * 16);
        upd2(acc, t1, t2);

        f32x16 acc2 = {0,0,0,0, 0,0,0,0, 0,0,0,0, 0,0,0,0};
#pragma unroll
        for (int s = 0; s < 5; ++s)
            acc2 = __builtin_amdgcn_mfma_f32_32x32x16_bf16(fB[s], bfr[s], acc2, 0, 0, 0);
#pragma unroll
        for (int s = 0; s < 5; ++s) fB[s] = *(const bf16x8*)(ap + 32 * KROW + s * 16);
        ap += 64 * KROW;
        upd2(acc2, t1, t2);
    }

    float2 o; o.x = t1; o.y = t2;
    *(float2*)(top2 + (size_t)q * 64 + (size_t)(cs * 2 + laneh) * 2) = o;
}

// ---------------- kernel 4: per-query threshold = 8th of 64 view-top-2s ----
// Safety: each value is a distinct code's bf16 score; at most 7 codes exceed
// the global bf16 8th-best => T_q <= bf16-8th-best. Ties over-evict => lower
// T => safe. Stores T_q - DELTA (the collect threshold).
__global__ __launch_bounds__(256) void k_thresh(const float* __restrict__ top2,
                                                float* __restrict__ thrm) {
    const int lane = threadIdx.x & 63;
    const int q = blockIdx.x * 4 + (threadIdx.x >> 6);
    float v = top2[(size_t)q * 64 + lane];
    float mx = -FLT_MAX;
#pragma unroll
    for (int r = 0; r < 8; ++r) {
        mx = v;
#pragma unroll
        for (int off = 32; off; off >>= 1) mx = fmaxf(mx, __shfl_xor(mx, off, 64));
        v = (v == mx) ? -FLT_MAX : v;
    }
    if (lane == 0) thrm[q] = mx - DELTA;
}

// ---------------- kernel 5: scan #2 — collect survivors --------------------
// Same scan; per element one compare vs per-query threshold; rare appends to
// private per-(query,view) buffer (no atomics, no top-k maintenance).
__global__ __launch_bounds__(256) void k_collect(const unsigned short* __restrict__ cbb_,
                                                 const unsigned short* __restrict__ xb_,
                                                 const float* __restrict__ thrm,
                                                 unsigned short* __restrict__ cand,
                                                 unsigned short* __restrict__ cnt) {
    const __bf16* cbv = (const __bf16*)cbb_;
    const __bf16* xbv = (const __bf16*)xb_;
    const int tid = threadIdx.x, lane = tid & 63, wv = tid >> 6;
    const int laneh = lane >> 5;
    const int qg = blockIdx.x >> 4;
    const int cs = blockIdx.x & 15;
    const int q = qg * 128 + wv * 32 + (lane & 31);
    const int cbase = cs * CHUNK;
    const int view = cs * 2 + laneh;

    bf16x8 bfr[5];
    {
        const __bf16* bp = xbv + (size_t)q * KROW + laneh * 8;
#pragma unroll
        for (int s = 0; s < 5; ++s) bfr[s] = *(const bf16x8*)(bp + s * 16);
    }
    const float Tm = thrm[q];
    unsigned c = 0;
    unsigned short* buf = cand + ((size_t)q * NVIEW + view) * CAP;

    const __bf16* ap = cbv + (size_t)(cbase + (lane & 31)) * KROW + laneh * 8;
    bf16x8 fA[5], fB[5];
#pragma unroll
    for (int s = 0; s < 5; ++s) fA[s] = *(const bf16x8*)(ap + s * 16);
#pragma unroll
    for (int s = 0; s < 5; ++s) fB[s] = *(const bf16x8*)(ap + 32 * KROW + s * 16);
    ap += 64 * KROW;

    for (int it = 0; it < NITER; it += 2) {
        f32x16 acc = {0,0,0,0, 0,0,0,0, 0,0,0,0, 0,0,0,0};
#pragma unroll
        for (int s = 0; s < 5; ++s)
            acc = __builtin_amdgcn_mfma_f32_32x32x16_bf16(fA[s], bfr[s], acc, 0, 0, 0);
#pragma unroll
        for (int s = 0; s < 5; ++s) fA[s] = *(const bf16x8*)(ap + s * 16);
        {
            const int code0 = cbase + it * 32 + 4 * laneh;
#pragma unroll
            for (int j = 0; j < 16; ++j) {
                if (acc[j] >= Tm) {
                    if (c < CAP) buf[c] = (unsigned short)(code0 + RJ(j));
                    ++c;
                }
            }
        }
        f32x16 acc2 = {0,0,0,0, 0,0,0,0, 0,0,0,0, 0,0,0,0};
#pragma unroll
        for (int s = 0; s < 5; ++s)
            acc2 = __builtin_amdgcn_mfma_f32_32x32x16_bf16(fB[s], bfr[s], acc2, 0, 0, 0);
#pragma unroll
        for (int s = 0; s < 5; ++s) fB[s] = *(const bf16x8*)(ap + 32 * KROW + s * 16);
        ap += 64 * KROW;
        {
            const int code0 = cbase + (it + 1) * 32 + 4 * laneh;
#pragma unroll
            for (int j = 0; j < 16; ++j) {
                if (acc2[j] >= Tm) {
                    if (c < CAP) buf[c] = (unsigned short)(code0 + RJ(j));
                    ++c;
                }
            }
        }
    }
    cnt[(size_t)q * NVIEW + view] = (unsigned short)(c < CAP ? c : CAP);
}

// ---- numpy pairwise_sum (n=64 base case), mul/add NOT contracted ----------
__device__ __forceinline__ float np_pairwise_sq64(const float* __restrict__ p) {
    float r[8];
#pragma unroll
    for (int j = 0; j < 8; ++j) r[j] = __fmul_rn(p[j], p[j]);
#pragma unroll
    for (int k = 1; k < 8; ++k)
#pragma unroll
        for (int j = 0; j < 8; ++j)
            r[j] = __fadd_rn(r[j], __fmul_rn(p[8 * k + j], p[8 * k + j]));
    const float t01 = __fadd_rn(r[0], r[1]);
    const float t23 = __fadd_rn(r[2], r[3]);
    const float t45 = __fadd_rn(r[4], r[5]);
    const float t67 = __fadd_rn(r[6], r[7]);
    return __fadd_rn(__fadd_rn(t01, t23), __fadd_rn(t45, t67));
}

// reference-f32 score key: ((2*xc - x2) - c2), xc = sequential fma chain
__device__ __forceinline__ float score_key(const float* __restrict__ xr,
                                           const float* __restrict__ cr,
                                           float x2e) {
    float xc = 0.f;
#pragma unroll
    for (int d = 0; d < DIM; ++d) xc = __builtin_fmaf(cr[d], xr[d], xc);
    const float c2e = np_pairwise_sq64(cr);
    return __fsub_rn(__fsub_rn(__fmul_rn(2.0f, xc), x2e), c2e);
}

// ---------------- kernel 6: exact-f32 rescore of survivors -----------------
// one wave per query; compacted survivor list via prefix over 32 view counts.
// ids written as FLOAT32 VALUES (harness reads whole d_out as f32).
__global__ __launch_bounds__(256) void k_rescore(const float* __restrict__ x,
                                                 const float* __restrict__ cb,
                                                 const unsigned short* __restrict__ cand,
                                                 const unsigned short* __restrict__ cnt,
                                                 float* __restrict__ out0,
                                                 float* __restrict__ out1) {
    const int lane = threadIdx.x & 63;
    const int q = blockIdx.x * 4 + (threadIdx.x >> 6);
    const float* xr = x + ((size_t)q << 6);
    const float x2e = np_pairwise_sq64(xr);
    const unsigned short* cq = cnt + (size_t)q * NVIEW;

    int base[6], view[6];
#pragma unroll
    for (int s = 0; s < 6; ++s) { base[s] = 0; view[s] = 0; }
    int cu = 0;
#pragma unroll
    for (int v = 0; v < NVIEW; ++v) {
        const int cv = cq[v];
#pragma unroll
        for (int s = 0; s < 6; ++s) {
            const int p = lane + 64 * s;
            if (p >= cu) { view[s] = v; base[s] = cu; }
        }
        cu += cv;
    }
    const int total = cu;

    float vv[6]; int id[6];
#pragma unroll
    for (int s = 0; s < 6; ++s) {
        const int p = lane + 64 * s;
        if (p < total) {
            const int idv = cand[((size_t)q * NVIEW + view[s]) * CAP + (p - base[s])];
            id[s] = idv;
            vv[s] = score_key(xr, cb + (size_t)idv * DIM, x2e);
        } else {
            id[s] = 1 << 20;
            vv[s] = -FLT_MAX;
        }
    }

    double accd = 0.0;
#pragma unroll
    for (int rep = 0; rep < KC; ++rep) {
        float bv = vv[0]; int bi = id[0];
#pragma unroll
        for (int s = 1; s < 6; ++s)
            if (vv[s] > bv || (vv[s] == bv && id[s] < bi)) { bv = vv[s]; bi = id[s]; }
#pragma unroll
        for (int off = 32; off; off >>= 1) {
            const float ov = __shfl_xor(bv, off, 64);
            const int   oi = __shfl_xor(bi, off, 64);
            if (ov > bv || (ov == bv && oi < bi)) { bv = ov; bi = oi; }
        }
        if (lane == 0) out1[q * KC + rep] = (float)bi;   // rank-ordered ids
        accd += (double)cb[(size_t)bi * DIM + lane];     // lane = dim
#pragma unroll
        for (int s = 0; s < 6; ++s) if (id[s] == bi) vv[s] = -FLT_MAX;
    }
    out0[(size_t)q * DIM + lane] = (float)(accd * 0.125);
}

// ---------------------------------------------------------------------------
extern "C" void kernel_launch(void* const* d_in, const int* in_sizes, int n_in,
                              void* d_out, int out_size, void* d_ws, size_t ws_size,
                              hipStream_t stream) {
    const float* x  = (const float*)d_in[0];   // [8192][64]
    const float* cb = (const float*)d_in[1];   // [65536][64]

    char* ws = (char*)d_ws;
    unsigned short* cbb  = (unsigned short*)ws;                       // 10.0 MB
    unsigned short* xb   = (unsigned short*)(ws + (size_t)NCODES * KROW * 2);          // 1.25 MB (also absorbs prefetch overrun)
    float*          top2 = (float*)(ws + (size_t)NCODES * KROW * 2
                                       + (size_t)NQ * KROW * 2);      // 2 MB
    float*          thrm = (float*)((char*)top2 + (size_t)NQ * 64 * 4);          // 32 KB
    unsigned short* cnt  = (unsigned short*)((char*)thrm + (size_t)NQ * 4);      // 512 KB
    unsigned short* cand = (unsigned short*)((char*)cnt + (size_t)NQ * NVIEW * 2); // 10.5 MB

    float* out0 = (float*)d_out;                       // [8192][64] f32
    float* out1 = (float*)d_out + (size_t)NQ * DIM;    // [8192][8] ids-as-f32

    k_conv_cb<<<NCODES / 256, 256, 0, stream>>>(cb, cbb);
    k_conv_x <<<NQ / 256,     256, 0, stream>>>(x, xb);
    k_scanA  <<<1024,         256, 0, stream>>>(cbb, xb, top2);
    k_thresh <<<NQ / 4,       256, 0, stream>>>(top2, thrm);
    k_collect<<<1024,         256, 0, stream>>>(cbb, xb, thrm, cand, cnt);
    k_rescore<<<NQ / 4,       256, 0, stream>>>(x, cb, cand, cnt, out0, out1);
}

// Round 8
// 243.809 us; speedup vs baseline: 37.3195x; 1.3710x over previous
//
#include <hip/hip_runtime.h>
#include <float.h>

#define DIM     64
#define NCODES  65536
#define KC      8
#define NQ      8192        // B*S
#define KROW    80          // padded bf16 row: 64 data + c2_hi + c2_lo + zeros (5 mfma k-steps)
#define CS      32          // code splits
#define CHUNK   (NCODES/CS) // 2048 codes per wave-scan
#define NITER   (CHUNK/32)  // 64 tiles
#define NVIEW   64          // CS * 2 lane-halves (disjoint code views per query)
#define CAP     12          // candidate slots per (query,view)
#define DELTA   1.5f        // collect margin: >= 2 * worst bf16-vs-exact score error
#define MAXSUR  384         // rescore capacity (6 x 64)

typedef __bf16 bf16x8 __attribute__((ext_vector_type(8)));
typedef float  f32x16 __attribute__((ext_vector_type(16)));
typedef unsigned short u16x8 __attribute__((ext_vector_type(8)));

static __device__ __forceinline__ unsigned short f2bf(float f) {
    unsigned u = __float_as_uint(f);
    u += 0x7FFFu + ((u >> 16) & 1u);
    return (unsigned short)(u >> 16);
}

#define RJ(j) (((j) & 3) + 8 * ((j) >> 2))   // C/D row for acc reg j (HW-verified)

// ---------------- kernel 1: codebook -> augmented bf16 rows (c2 inline) ----
__global__ __launch_bounds__(256) void k_conv_cb(const float* __restrict__ cb,
                                                 unsigned short* __restrict__ cbb) {
    int n = blockIdx.x * 256 + threadIdx.x;
    const float4* src = (const float4*)(cb + (size_t)n * DIM);
    unsigned short* dst = cbb + (size_t)n * KROW;
    float s = 0.f;
#pragma unroll
    for (int c = 0; c < 8; ++c) {
        float4 f0 = src[2 * c], f1 = src[2 * c + 1];
        s = fmaf(f0.x, f0.x, s); s = fmaf(f0.y, f0.y, s);
        s = fmaf(f0.z, f0.z, s); s = fmaf(f0.w, f0.w, s);
        s = fmaf(f1.x, f1.x, s); s = fmaf(f1.y, f1.y, s);
        s = fmaf(f1.z, f1.z, s); s = fmaf(f1.w, f1.w, s);
        u16x8 o;
        o[0] = f2bf(2.f * f0.x); o[1] = f2bf(2.f * f0.y);
        o[2] = f2bf(2.f * f0.z); o[3] = f2bf(2.f * f0.w);
        o[4] = f2bf(2.f * f1.x); o[5] = f2bf(2.f * f1.y);
        o[6] = f2bf(2.f * f1.z); o[7] = f2bf(2.f * f1.w);
        *(u16x8*)(dst + c * 8) = o;
    }
    unsigned short hi = f2bf(s);
    float hif = __uint_as_float(((unsigned)hi) << 16);
    unsigned short lo = f2bf(s - hif);
    u16x8 p = { (unsigned short)(hi ^ 0x8000u), (unsigned short)(lo ^ 0x8000u),
                0, 0, 0, 0, 0, 0 };
    *(u16x8*)(dst + 64) = p;
    u16x8 z = {0, 0, 0, 0, 0, 0, 0, 0};
    *(u16x8*)(dst + 72) = z;
}

// ---------------- kernel 2: x -> augmented bf16 rows -----------------------
__global__ __launch_bounds__(256) void k_conv_x(const float* __restrict__ x,
                                                unsigned short* __restrict__ xb) {
    int n = blockIdx.x * 256 + threadIdx.x;
    const float4* src = (const float4*)(x + (size_t)n * DIM);
    unsigned short* dst = xb + (size_t)n * KROW;
#pragma unroll
    for (int c = 0; c < 8; ++c) {
        float4 f0 = src[2 * c], f1 = src[2 * c + 1];
        u16x8 o;
        o[0] = f2bf(f0.x); o[1] = f2bf(f0.y); o[2] = f2bf(f0.z); o[3] = f2bf(f0.w);
        o[4] = f2bf(f1.x); o[5] = f2bf(f1.y); o[6] = f2bf(f1.z); o[7] = f2bf(f1.w);
        *(u16x8*)(dst + c * 8) = o;
    }
    u16x8 p = {0x3F80u, 0x3F80u, 0, 0, 0, 0, 0, 0};   // 1.0, 1.0
    *(u16x8*)(dst + 64) = p;
    u16x8 z = {0, 0, 0, 0, 0, 0, 0, 0};
    *(u16x8*)(dst + 72) = z;
}

// max of 16 acc values (compiler fuses fmaxf pairs into v_max3)
__device__ __forceinline__ float tmax16(const f32x16& a) {
    float m0 = fmaxf(fmaxf(a[0],  a[1]),  fmaxf(a[2],  a[3]));
    float m1 = fmaxf(fmaxf(a[4],  a[5]),  fmaxf(a[6],  a[7]));
    float m2 = fmaxf(fmaxf(a[8],  a[9]),  fmaxf(a[10], a[11]));
    float m3 = fmaxf(fmaxf(a[12], a[13]), fmaxf(a[14], a[15]));
    return fmaxf(fmaxf(m0, m1), fmaxf(m2, m3));
}

// branchless top-2 update (monotone: safe to run even when nothing improves)
__device__ __forceinline__ void upd2(const f32x16& acc, float& t1, float& t2) {
#pragma unroll
    for (int j = 0; j < 16; ++j) {
        const float v = acc[j];
        const float tmp = fminf(t1, v);
        t1 = fmaxf(t1, v);
        t2 = fmaxf(t2, tmp);
    }
}

// ---------------- kernel 3: scan #1 — per-view top-2 values ----------------
// grid 1024 = (qg 0..31) x (cs 0..31). block 4 waves; wave covers 64 queries
// (two 32-query B-fragment sets, QSETS=2) x 32 codes/tile. Depth-2 prefetch.
__global__ __launch_bounds__(256, 4) void k_scanA(const unsigned short* __restrict__ cbb_,
                                                  const unsigned short* __restrict__ xb_,
                                                  float* __restrict__ top2) {
    const __bf16* cbv = (const __bf16*)cbb_;
    const __bf16* xbv = (const __bf16*)xb_;
    const int tid = threadIdx.x, lane = tid & 63, wv = tid >> 6;
    const int laneh = lane >> 5;
    const int qg = blockIdx.x >> 5;     // 0..31
    const int cs = blockIdx.x & 31;     // 0..31
    const int qA = qg * 256 + wv * 64 + (lane & 31);
    const int qB = qA + 32;
    const int cbase = cs * CHUNK;
    const int view = cs * 2 + laneh;

    bf16x8 bfrA[5], bfrB[5];
    {
        const __bf16* bp = xbv + (size_t)qA * KROW + laneh * 8;
#pragma unroll
        for (int s = 0; s < 5; ++s) bfrA[s] = *(const bf16x8*)(bp + s * 16);
        bp += (size_t)32 * KROW;
#pragma unroll
        for (int s = 0; s < 5; ++s) bfrB[s] = *(const bf16x8*)(bp + s * 16);
    }

    float t1a = -FLT_MAX, t2a = -FLT_MAX, t1b = -FLT_MAX, t2b = -FLT_MAX;

    const __bf16* ap = cbv + (size_t)(cbase + (lane & 31)) * KROW + laneh * 8;
    bf16x8 fA[5], fB[5];
#pragma unroll
    for (int s = 0; s < 5; ++s) fA[s] = *(const bf16x8*)(ap + s * 16);
#pragma unroll
    for (int s = 0; s < 5; ++s) fB[s] = *(const bf16x8*)(ap + 32 * KROW + s * 16);
    ap += 64 * KROW;

    for (int it = 0; it < NITER; it += 2) {
        {   // tile it (fA)
            f32x16 acc = {0,0,0,0, 0,0,0,0, 0,0,0,0, 0,0,0,0};
#pragma unroll
            for (int s = 0; s < 5; ++s)
                acc = __builtin_amdgcn_mfma_f32_32x32x16_bf16(fA[s], bfrA[s], acc, 0, 0, 0);
            if (__any(tmax16(acc) > t2a)) upd2(acc, t1a, t2a);
            f32x16 acc2 = {0,0,0,0, 0,0,0,0, 0,0,0,0, 0,0,0,0};
#pragma unroll
            for (int s = 0; s < 5; ++s)
                acc2 = __builtin_amdgcn_mfma_f32_32x32x16_bf16(fA[s], bfrB[s], acc2, 0, 0, 0);
#pragma unroll
            for (int s = 0; s < 5; ++s) fA[s] = *(const bf16x8*)(ap + s * 16);  // prefetch it+2
            if (__any(tmax16(acc2) > t2b)) upd2(acc2, t1b, t2b);
        }
        {   // tile it+1 (fB)
            f32x16 acc = {0,0,0,0, 0,0,0,0, 0,0,0,0, 0,0,0,0};
#pragma unroll
            for (int s = 0; s < 5; ++s)
                acc = __builtin_amdgcn_mfma_f32_32x32x16_bf16(fB[s], bfrA[s], acc, 0, 0, 0);
            if (__any(tmax16(acc) > t2a)) upd2(acc, t1a, t2a);
            f32x16 acc2 = {0,0,0,0, 0,0,0,0, 0,0,0,0, 0,0,0,0};
#pragma unroll
            for (int s = 0; s < 5; ++s)
                acc2 = __builtin_amdgcn_mfma_f32_32x32x16_bf16(fB[s], bfrB[s], acc2, 0, 0, 0);
#pragma unroll
            for (int s = 0; s < 5; ++s) fB[s] = *(const bf16x8*)(ap + 32 * KROW + s * 16); // it+3
            if (__any(tmax16(acc2) > t2b)) upd2(acc2, t1b, t2b);
        }
        ap += 64 * KROW;
    }

    float2 oa; oa.x = t1a; oa.y = t2a;
    float2 ob; ob.x = t1b; ob.y = t2b;
    *(float2*)(top2 + (size_t)qA * 128 + (size_t)view * 2) = oa;
    *(float2*)(top2 + (size_t)qB * 128 + (size_t)view * 2) = ob;
}

// ---------------- kernel 4: per-query threshold = 8th of 128 view-top-2s ---
// Safety: each value is a distinct code's bf16 score; at most 7 codes exceed
// the global bf16 8th-best => T_q <= bf16-8th-best. Ties over-evict => lower
// T => more survivors => safe. Stores T_q - DELTA.
__global__ __launch_bounds__(256) void k_thresh(const float* __restrict__ top2,
                                                float* __restrict__ thrm) {
    const int lane = threadIdx.x & 63;
    const int q = blockIdx.x * 4 + (threadIdx.x >> 6);
    float2 t = *(const float2*)(top2 + (size_t)q * 128 + lane * 2);
    float v0 = t.x, v1 = t.y;
    float mx = -FLT_MAX;
#pragma unroll
    for (int r = 0; r < 8; ++r) {
        mx = fmaxf(v0, v1);
#pragma unroll
        for (int off = 32; off; off >>= 1) mx = fmaxf(mx, __shfl_xor(mx, off, 64));
        if (v0 == mx) v0 = -FLT_MAX;
        if (v1 == mx) v1 = -FLT_MAX;
    }
    if (lane == 0) thrm[q] = mx - DELTA;
}

// ---------------- kernel 5: scan #2 — collect survivors --------------------
__global__ __launch_bounds__(256, 4) void k_collect(const unsigned short* __restrict__ cbb_,
                                                    const unsigned short* __restrict__ xb_,
                                                    const float* __restrict__ thrm,
                                                    unsigned short* __restrict__ cand,
                                                    unsigned short* __restrict__ cnt) {
    const __bf16* cbv = (const __bf16*)cbb_;
    const __bf16* xbv = (const __bf16*)xb_;
    const int tid = threadIdx.x, lane = tid & 63, wv = tid >> 6;
    const int laneh = lane >> 5;
    const int qg = blockIdx.x >> 5;
    const int cs = blockIdx.x & 31;
    const int qA = qg * 256 + wv * 64 + (lane & 31);
    const int qB = qA + 32;
    const int cbase = cs * CHUNK;
    const int view = cs * 2 + laneh;

    bf16x8 bfrA[5], bfrB[5];
    {
        const __bf16* bp = xbv + (size_t)qA * KROW + laneh * 8;
#pragma unroll
        for (int s = 0; s < 5; ++s) bfrA[s] = *(const bf16x8*)(bp + s * 16);
        bp += (size_t)32 * KROW;
#pragma unroll
        for (int s = 0; s < 5; ++s) bfrB[s] = *(const bf16x8*)(bp + s * 16);
    }
    const float TmA = thrm[qA];
    const float TmB = thrm[qB];
    unsigned cA = 0, cB = 0;
    unsigned short* bufA = cand + ((size_t)qA * NVIEW + view) * CAP;
    unsigned short* bufB = cand + ((size_t)qB * NVIEW + view) * CAP;

    const __bf16* ap = cbv + (size_t)(cbase + (lane & 31)) * KROW + laneh * 8;
    bf16x8 fA[5], fB[5];
#pragma unroll
    for (int s = 0; s < 5; ++s) fA[s] = *(const bf16x8*)(ap + s * 16);
#pragma unroll
    for (int s = 0; s < 5; ++s) fB[s] = *(const bf16x8*)(ap + 32 * KROW + s * 16);
    ap += 64 * KROW;

    for (int it = 0; it < NITER; it += 2) {
        {   // tile it (fA)
            const int code0 = cbase + it * 32 + 4 * laneh;
            f32x16 acc = {0,0,0,0, 0,0,0,0, 0,0,0,0, 0,0,0,0};
#pragma unroll
            for (int s = 0; s < 5; ++s)
                acc = __builtin_amdgcn_mfma_f32_32x32x16_bf16(fA[s], bfrA[s], acc, 0, 0, 0);
            if (__any(tmax16(acc) >= TmA)) {
#pragma unroll
                for (int j = 0; j < 16; ++j)
                    if (acc[j] >= TmA) { if (cA < CAP) bufA[cA] = (unsigned short)(code0 + RJ(j)); ++cA; }
            }
            f32x16 acc2 = {0,0,0,0, 0,0,0,0, 0,0,0,0, 0,0,0,0};
#pragma unroll
            for (int s = 0; s < 5; ++s)
                acc2 = __builtin_amdgcn_mfma_f32_32x32x16_bf16(fA[s], bfrB[s], acc2, 0, 0, 0);
#pragma unroll
            for (int s = 0; s < 5; ++s) fA[s] = *(const bf16x8*)(ap + s * 16);
            if (__any(tmax16(acc2) >= TmB)) {
#pragma unroll
                for (int j = 0; j < 16; ++j)
                    if (acc2[j] >= TmB) { if (cB < CAP) bufB[cB] = (unsigned short)(code0 + RJ(j)); ++cB; }
            }
        }
        {   // tile it+1 (fB)
            const int code0 = cbase + (it + 1) * 32 + 4 * laneh;
            f32x16 acc = {0,0,0,0, 0,0,0,0, 0,0,0,0, 0,0,0,0};
#pragma unroll
            for (int s = 0; s < 5; ++s)
                acc = __builtin_amdgcn_mfma_f32_32x32x16_bf16(fB[s], bfrA[s], acc, 0, 0, 0);
            if (__any(tmax16(acc) >= TmA)) {
#pragma unroll
                for (int j = 0; j < 16; ++j)
                    if (acc[j] >= TmA) { if (cA < CAP) bufA[cA] = (unsigned short)(code0 + RJ(j)); ++cA; }
            }
            f32x16 acc2 = {0,0,0,0, 0,0,0,0, 0,0,0,0, 0,0,0,0};
#pragma unroll
            for (int s = 0; s < 5; ++s)
                acc2 = __builtin_amdgcn_mfma_f32_32x32x16_bf16(fB[s], bfrB[s], acc2, 0, 0, 0);
#pragma unroll
            for (int s = 0; s < 5; ++s) fB[s] = *(const bf16x8*)(ap + 32 * KROW + s * 16);
            if (__any(tmax16(acc2) >= TmB)) {
#pragma unroll
                for (int j = 0; j < 16; ++j)
                    if (acc2[j] >= TmB) { if (cB < CAP) bufB[cB] = (unsigned short)(code0 + RJ(j)); ++cB; }
            }
        }
        ap += 64 * KROW;
    }
    cnt[(size_t)qA * NVIEW + view] = (unsigned short)(cA < CAP ? cA : CAP);
    cnt[(size_t)qB * NVIEW + view] = (unsigned short)(cB < CAP ? cB : CAP);
}

// ---- numpy pairwise_sum (n=64 base case), mul/add NOT contracted ----------
__device__ __forceinline__ float np_pairwise_sq64(const float* __restrict__ p) {
    float r[8];
#pragma unroll
    for (int j = 0; j < 8; ++j) r[j] = __fmul_rn(p[j], p[j]);
#pragma unroll
    for (int k = 1; k < 8; ++k)
#pragma unroll
        for (int j = 0; j < 8; ++j)
            r[j] = __fadd_rn(r[j], __fmul_rn(p[8 * k + j], p[8 * k + j]));
    const float t01 = __fadd_rn(r[0], r[1]);
    const float t23 = __fadd_rn(r[2], r[3]);
    const float t45 = __fadd_rn(r[4], r[5]);
    const float t67 = __fadd_rn(r[6], r[7]);
    return __fadd_rn(__fadd_rn(t01, t23), __fadd_rn(t45, t67));
}

// reference-f32 score key: ((2*xc - x2) - c2), xc = sequential fma chain
__device__ __forceinline__ float score_key(const float* __restrict__ xr,
                                           const float* __restrict__ cr,
                                           float x2e) {
    float xc = 0.f;
#pragma unroll
    for (int d = 0; d < DIM; ++d) xc = __builtin_fmaf(cr[d], xr[d], xc);
    const float c2e = np_pairwise_sq64(cr);
    return __fsub_rn(__fsub_rn(__fmul_rn(2.0f, xc), x2e), c2e);
}

// ---------------- kernel 6: exact-f32 rescore of survivors -----------------
// one wave per query; per-lane view counts -> wave prefix-sum -> LDS compact.
// ids written as FLOAT32 VALUES (harness reads whole d_out as f32).
__global__ __launch_bounds__(256) void k_rescore(const float* __restrict__ x,
                                                 const float* __restrict__ cb,
                                                 const unsigned short* __restrict__ cand,
                                                 const unsigned short* __restrict__ cnt,
                                                 float* __restrict__ out0,
                                                 float* __restrict__ out1) {
    __shared__ int s_ids[4][MAXSUR];
    const int lane = threadIdx.x & 63;
    const int wvi = threadIdx.x >> 6;
    const int q = blockIdx.x * 4 + wvi;
    const float* xr = x + ((size_t)q << 6);
    const float x2e = np_pairwise_sq64(xr);

    // lane = view; compact all survivors into LDS
    const int c = cnt[(size_t)q * NVIEW + lane];
    int p = c;
#pragma unroll
    for (int off = 1; off < 64; off <<= 1) {
        const int t = __shfl_up(p, off, 64);
        if (lane >= off) p += t;
    }
    const int excl = p - c;
    int total = __shfl(p, 63, 64);
    if (total > MAXSUR) total = MAXSUR;
    const unsigned short* src = cand + ((size_t)q * NVIEW + lane) * CAP;
    for (int k = 0; k < c; ++k) {
        const int dst = excl + k;
        if (dst < MAXSUR) s_ids[wvi][dst] = src[k];
    }
    __syncthreads();

    float vv[6]; int id[6];
#pragma unroll
    for (int s = 0; s < 6; ++s) {
        vv[s] = -FLT_MAX; id[s] = 1 << 20;
        if (s * 64 < total) {
            const int pos = lane + 64 * s;
            if (pos < total) {
                const int idv = s_ids[wvi][pos];
                id[s] = idv;
                vv[s] = score_key(xr, cb + (size_t)idv * DIM, x2e);
            }
        }
    }

    double accd = 0.0;
#pragma unroll
    for (int rep = 0; rep < KC; ++rep) {
        float bv = vv[0]; int bi = id[0];
#pragma unroll
        for (int s = 1; s < 6; ++s)
            if (vv[s] > bv || (vv[s] == bv && id[s] < bi)) { bv = vv[s]; bi = id[s]; }
#pragma unroll
        for (int off = 32; off; off >>= 1) {
            const float ov = __shfl_xor(bv, off, 64);
            const int   oi = __shfl_xor(bi, off, 64);
            if (ov > bv || (ov == bv && oi < bi)) { bv = ov; bi = oi; }
        }
        if (lane == 0) out1[q * KC + rep] = (float)bi;   // rank-ordered ids
        accd += (double)cb[(size_t)bi * DIM + lane];     // lane = dim
#pragma unroll
        for (int s = 0; s < 6; ++s) if (id[s] == bi) vv[s] = -FLT_MAX;
    }
    out0[(size_t)q * DIM + lane] = (float)(accd * 0.125);
}

// ---------------------------------------------------------------------------
extern "C" void kernel_launch(void* const* d_in, const int* in_sizes, int n_in,
                              void* d_out, int out_size, void* d_ws, size_t ws_size,
                              hipStream_t stream) {
    const float* x  = (const float*)d_in[0];   // [8192][64]
    const float* cb = (const float*)d_in[1];   // [65536][64]

    char* ws = (char*)d_ws;
    unsigned short* cbb  = (unsigned short*)ws;                                  // 10.0 MB
    unsigned short* xb   = (unsigned short*)(ws + (size_t)NCODES * KROW * 2);    // 1.25 MB (absorbs prefetch overrun)
    float*          top2 = (float*)(ws + (size_t)NCODES * KROW * 2
                                       + (size_t)NQ * KROW * 2);                 // 4 MB
    float*          thrm = (float*)((char*)top2 + (size_t)NQ * 128 * 4);         // 32 KB
    unsigned short* cnt  = (unsigned short*)((char*)thrm + (size_t)NQ * 4);      // 1 MB
    unsigned short* cand = (unsigned short*)((char*)cnt + (size_t)NQ * NVIEW * 2); // 12.6 MB

    float* out0 = (float*)d_out;                       // [8192][64] f32
    float* out1 = (float*)d_out + (size_t)NQ * DIM;    // [8192][8] ids-as-f32

    k_conv_cb<<<NCODES / 256, 256, 0, stream>>>(cb, cbb);
    k_conv_x <<<NQ / 256,     256, 0, stream>>>(x, xb);
    k_scanA  <<<1024,         256, 0, stream>>>(cbb, xb, top2);
    k_thresh <<<NQ / 4,       256, 0, stream>>>(top2, thrm);
    k_collect<<<1024,         256, 0, stream>>>(cbb, xb, thrm, cand, cnt);
    k_rescore<<<NQ / 4,       256, 0, stream>>>(x, cb, cand, cnt, out0, out1);
}

// Round 9
// 218.086 us; speedup vs baseline: 41.7213x; 1.1179x over previous
//
#include <hip/hip_runtime.h>
#include <float.h>

#define DIM     64
#define NCODES  65536
#define KC      8
#define NQ      8192        // B*S
#define KROW    80          // padded bf16 row: 64 data + c2_hi + c2_lo + zeros (5 mfma k-steps)
#define CS      32          // code splits
#define CHUNK   (NCODES/CS) // 2048 codes per wave-scan
#define NITER   (CHUNK/32)  // 64 tiles
#define NVIEW   64          // CS * 2 lane-halves (disjoint code views per query)
#define CAP     12          // candidate slots per (query,view)
#define DELTA   1.5f        // collect margin: >= 2 * worst bf16-vs-exact score error
#define MAXSUR  384         // rescore capacity (6 x 64)

typedef __bf16 bf16x8 __attribute__((ext_vector_type(8)));
typedef float  f32x16 __attribute__((ext_vector_type(16)));
typedef unsigned short u16x8 __attribute__((ext_vector_type(8)));

static __device__ __forceinline__ unsigned short f2bf(float f) {
    unsigned u = __float_as_uint(f);
    u += 0x7FFFu + ((u >> 16) & 1u);
    return (unsigned short)(u >> 16);
}

#define RJ(j) (((j) & 3) + 8 * ((j) >> 2))   // C/D row for acc reg j (HW-verified)

// ---------------- kernel 1: codebook -> augmented bf16 rows (c2 inline) ----
__global__ __launch_bounds__(256) void k_conv_cb(const float* __restrict__ cb,
                                                 unsigned short* __restrict__ cbb) {
    int n = blockIdx.x * 256 + threadIdx.x;
    const float4* src = (const float4*)(cb + (size_t)n * DIM);
    unsigned short* dst = cbb + (size_t)n * KROW;
    float s = 0.f;
#pragma unroll
    for (int c = 0; c < 8; ++c) {
        float4 f0 = src[2 * c], f1 = src[2 * c + 1];
        s = fmaf(f0.x, f0.x, s); s = fmaf(f0.y, f0.y, s);
        s = fmaf(f0.z, f0.z, s); s = fmaf(f0.w, f0.w, s);
        s = fmaf(f1.x, f1.x, s); s = fmaf(f1.y, f1.y, s);
        s = fmaf(f1.z, f1.z, s); s = fmaf(f1.w, f1.w, s);
        u16x8 o;
        o[0] = f2bf(2.f * f0.x); o[1] = f2bf(2.f * f0.y);
        o[2] = f2bf(2.f * f0.z); o[3] = f2bf(2.f * f0.w);
        o[4] = f2bf(2.f * f1.x); o[5] = f2bf(2.f * f1.y);
        o[6] = f2bf(2.f * f1.z); o[7] = f2bf(2.f * f1.w);
        *(u16x8*)(dst + c * 8) = o;
    }
    unsigned short hi = f2bf(s);
    float hif = __uint_as_float(((unsigned)hi) << 16);
    unsigned short lo = f2bf(s - hif);
    u16x8 p = { (unsigned short)(hi ^ 0x8000u), (unsigned short)(lo ^ 0x8000u),
                0, 0, 0, 0, 0, 0 };
    *(u16x8*)(dst + 64) = p;
    u16x8 z = {0, 0, 0, 0, 0, 0, 0, 0};
    *(u16x8*)(dst + 72) = z;
}

// ---------------- kernel 2: x -> augmented bf16 rows -----------------------
__global__ __launch_bounds__(256) void k_conv_x(const float* __restrict__ x,
                                                unsigned short* __restrict__ xb) {
    int n = blockIdx.x * 256 + threadIdx.x;
    const float4* src = (const float4*)(x + (size_t)n * DIM);
    unsigned short* dst = xb + (size_t)n * KROW;
#pragma unroll
    for (int c = 0; c < 8; ++c) {
        float4 f0 = src[2 * c], f1 = src[2 * c + 1];
        u16x8 o;
        o[0] = f2bf(f0.x); o[1] = f2bf(f0.y); o[2] = f2bf(f0.z); o[3] = f2bf(f0.w);
        o[4] = f2bf(f1.x); o[5] = f2bf(f1.y); o[6] = f2bf(f1.z); o[7] = f2bf(f1.w);
        *(u16x8*)(dst + c * 8) = o;
    }
    u16x8 p = {0x3F80u, 0x3F80u, 0, 0, 0, 0, 0, 0};   // 1.0, 1.0
    *(u16x8*)(dst + 64) = p;
    u16x8 z = {0, 0, 0, 0, 0, 0, 0, 0};
    *(u16x8*)(dst + 72) = z;
}

// max of 16 acc values, nested-triple form so clang fuses to v_max3 (8 ops)
__device__ __forceinline__ float tmax16(const f32x16& a) {
    const float m0 = fmaxf(fmaxf(a[0],  a[1]),  a[2]);
    const float m1 = fmaxf(fmaxf(a[3],  a[4]),  a[5]);
    const float m2 = fmaxf(fmaxf(a[6],  a[7]),  a[8]);
    const float m3 = fmaxf(fmaxf(a[9],  a[10]), a[11]);
    const float m4 = fmaxf(fmaxf(a[12], a[13]), a[14]);
    const float n0 = fmaxf(fmaxf(m0, m1), m2);
    const float n1 = fmaxf(fmaxf(m3, m4), a[15]);
    return fmaxf(n0, n1);
}

// ---------------- kernel 3: scan #1 — per-view top-1 values ----------------
// grid 1024 = (qg 0..31) x (cs 0..31). block 4 waves; wave covers 64 queries
// (two 32-query B-fragment sets) x 32 codes/tile. Depth-2 prefetch.
// Selection is a single running max per (query, lane-half): no branches.
__global__ __launch_bounds__(256, 4) void k_scanA(const unsigned short* __restrict__ cbb_,
                                                  const unsigned short* __restrict__ xb_,
                                                  float* __restrict__ top1) {
    const __bf16* cbv = (const __bf16*)cbb_;
    const __bf16* xbv = (const __bf16*)xb_;
    const int tid = threadIdx.x, lane = tid & 63, wv = tid >> 6;
    const int laneh = lane >> 5;
    const int qg = blockIdx.x >> 5;     // 0..31
    const int cs = blockIdx.x & 31;     // 0..31
    const int qA = qg * 256 + wv * 64 + (lane & 31);
    const int qB = qA + 32;
    const int cbase = cs * CHUNK;
    const int view = cs * 2 + laneh;

    bf16x8 bfrA[5], bfrB[5];
    {
        const __bf16* bp = xbv + (size_t)qA * KROW + laneh * 8;
#pragma unroll
        for (int s = 0; s < 5; ++s) bfrA[s] = *(const bf16x8*)(bp + s * 16);
        bp += (size_t)32 * KROW;
#pragma unroll
        for (int s = 0; s < 5; ++s) bfrB[s] = *(const bf16x8*)(bp + s * 16);
    }

    float t1a = -FLT_MAX, t1b = -FLT_MAX;

    const __bf16* ap = cbv + (size_t)(cbase + (lane & 31)) * KROW + laneh * 8;
    bf16x8 fA[5], fB[5];
#pragma unroll
    for (int s = 0; s < 5; ++s) fA[s] = *(const bf16x8*)(ap + s * 16);
#pragma unroll
    for (int s = 0; s < 5; ++s) fB[s] = *(const bf16x8*)(ap + 32 * KROW + s * 16);
    ap += 64 * KROW;

    for (int it = 0; it < NITER; it += 2) {
        {   // tile it (fA)
            f32x16 acc = {0,0,0,0, 0,0,0,0, 0,0,0,0, 0,0,0,0};
#pragma unroll
            for (int s = 0; s < 5; ++s)
                acc = __builtin_amdgcn_mfma_f32_32x32x16_bf16(fA[s], bfrA[s], acc, 0, 0, 0);
            t1a = fmaxf(t1a, tmax16(acc));
            f32x16 acc2 = {0,0,0,0, 0,0,0,0, 0,0,0,0, 0,0,0,0};
#pragma unroll
            for (int s = 0; s < 5; ++s)
                acc2 = __builtin_amdgcn_mfma_f32_32x32x16_bf16(fA[s], bfrB[s], acc2, 0, 0, 0);
#pragma unroll
            for (int s = 0; s < 5; ++s) fA[s] = *(const bf16x8*)(ap + s * 16);  // prefetch it+2
            t1b = fmaxf(t1b, tmax16(acc2));
        }
        {   // tile it+1 (fB)
            f32x16 acc = {0,0,0,0, 0,0,0,0, 0,0,0,0, 0,0,0,0};
#pragma unroll
            for (int s = 0; s < 5; ++s)
                acc = __builtin_amdgcn_mfma_f32_32x32x16_bf16(fB[s], bfrA[s], acc, 0, 0, 0);
            t1a = fmaxf(t1a, tmax16(acc));
            f32x16 acc2 = {0,0,0,0, 0,0,0,0, 0,0,0,0, 0,0,0,0};
#pragma unroll
            for (int s = 0; s < 5; ++s)
                acc2 = __builtin_amdgcn_mfma_f32_32x32x16_bf16(fB[s], bfrB[s], acc2, 0, 0, 0);
#pragma unroll
            for (int s = 0; s < 5; ++s) fB[s] = *(const bf16x8*)(ap + 32 * KROW + s * 16); // it+3
            t1b = fmaxf(t1b, tmax16(acc2));
        }
        ap += 64 * KROW;
    }

    top1[(size_t)qA * NVIEW + view] = t1a;
    top1[(size_t)qB * NVIEW + view] = t1b;
}

// ---------------- kernel 4: per-query threshold = 8th of 64 view maxima ----
// Safety: the top-8 view-winners are 8 DISTINCT codes (views are disjoint
// code ranges), each with bf16 score >= T  =>  T <= bf16-8th-best globally.
// Ties evict extra copies => lower T => more survivors => safe.
__global__ __launch_bounds__(256) void k_thresh(const float* __restrict__ top1,
                                                float* __restrict__ thrm) {
    const int lane = threadIdx.x & 63;
    const int q = blockIdx.x * 4 + (threadIdx.x >> 6);
    float v = top1[(size_t)q * NVIEW + lane];
    float mx = -FLT_MAX;
#pragma unroll
    for (int r = 0; r < 8; ++r) {
        mx = v;
#pragma unroll
        for (int off = 32; off; off >>= 1) mx = fmaxf(mx, __shfl_xor(mx, off, 64));
        if (v == mx) v = -FLT_MAX;
    }
    if (lane == 0) thrm[q] = mx - DELTA;
}

// ---------------- kernel 5: scan #2 — collect survivors --------------------
__global__ __launch_bounds__(256, 4) void k_collect(const unsigned short* __restrict__ cbb_,
                                                    const unsigned short* __restrict__ xb_,
                                                    const float* __restrict__ thrm,
                                                    unsigned short* __restrict__ cand,
                                                    unsigned short* __restrict__ cnt) {
    const __bf16* cbv = (const __bf16*)cbb_;
    const __bf16* xbv = (const __bf16*)xb_;
    const int tid = threadIdx.x, lane = tid & 63, wv = tid >> 6;
    const int laneh = lane >> 5;
    const int qg = blockIdx.x >> 5;
    const int cs = blockIdx.x & 31;
    const int qA = qg * 256 + wv * 64 + (lane & 31);
    const int qB = qA + 32;
    const int cbase = cs * CHUNK;
    const int view = cs * 2 + laneh;

    bf16x8 bfrA[5], bfrB[5];
    {
        const __bf16* bp = xbv + (size_t)qA * KROW + laneh * 8;
#pragma unroll
        for (int s = 0; s < 5; ++s) bfrA[s] = *(const bf16x8*)(bp + s * 16);
        bp += (size_t)32 * KROW;
#pragma unroll
        for (int s = 0; s < 5; ++s) bfrB[s] = *(const bf16x8*)(bp + s * 16);
    }
    const float TmA = thrm[qA];
    const float TmB = thrm[qB];
    unsigned cA = 0, cB = 0;
    unsigned short* bufA = cand + ((size_t)qA * NVIEW + view) * CAP;
    unsigned short* bufB = cand + ((size_t)qB * NVIEW + view) * CAP;

    const __bf16* ap = cbv + (size_t)(cbase + (lane & 31)) * KROW + laneh * 8;
    bf16x8 fA[5], fB[5];
#pragma unroll
    for (int s = 0; s < 5; ++s) fA[s] = *(const bf16x8*)(ap + s * 16);
#pragma unroll
    for (int s = 0; s < 5; ++s) fB[s] = *(const bf16x8*)(ap + 32 * KROW + s * 16);
    ap += 64 * KROW;

    for (int it = 0; it < NITER; it += 2) {
        {   // tile it (fA)
            const int code0 = cbase + it * 32 + 4 * laneh;
            f32x16 acc = {0,0,0,0, 0,0,0,0, 0,0,0,0, 0,0,0,0};
#pragma unroll
            for (int s = 0; s < 5; ++s)
                acc = __builtin_amdgcn_mfma_f32_32x32x16_bf16(fA[s], bfrA[s], acc, 0, 0, 0);
            if (__any(tmax16(acc) >= TmA)) {
#pragma unroll
                for (int j = 0; j < 16; ++j)
                    if (acc[j] >= TmA) { if (cA < CAP) bufA[cA] = (unsigned short)(code0 + RJ(j)); ++cA; }
            }
            f32x16 acc2 = {0,0,0,0, 0,0,0,0, 0,0,0,0, 0,0,0,0};
#pragma unroll
            for (int s = 0; s < 5; ++s)
                acc2 = __builtin_amdgcn_mfma_f32_32x32x16_bf16(fA[s], bfrB[s], acc2, 0, 0, 0);
#pragma unroll
            for (int s = 0; s < 5; ++s) fA[s] = *(const bf16x8*)(ap + s * 16);
            if (__any(tmax16(acc2) >= TmB)) {
#pragma unroll
                for (int j = 0; j < 16; ++j)
                    if (acc2[j] >= TmB) { if (cB < CAP) bufB[cB] = (unsigned short)(code0 + RJ(j)); ++cB; }
            }
        }
        {   // tile it+1 (fB)
            const int code0 = cbase + (it + 1) * 32 + 4 * laneh;
            f32x16 acc = {0,0,0,0, 0,0,0,0, 0,0,0,0, 0,0,0,0};
#pragma unroll
            for (int s = 0; s < 5; ++s)
                acc = __builtin_amdgcn_mfma_f32_32x32x16_bf16(fB[s], bfrA[s], acc, 0, 0, 0);
            if (__any(tmax16(acc) >= TmA)) {
#pragma unroll
                for (int j = 0; j < 16; ++j)
                    if (acc[j] >= TmA) { if (cA < CAP) bufA[cA] = (unsigned short)(code0 + RJ(j)); ++cA; }
            }
            f32x16 acc2 = {0,0,0,0, 0,0,0,0, 0,0,0,0, 0,0,0,0};
#pragma unroll
            for (int s = 0; s < 5; ++s)
                acc2 = __builtin_amdgcn_mfma_f32_32x32x16_bf16(fB[s], bfrB[s], acc2, 0, 0, 0);
#pragma unroll
            for (int s = 0; s < 5; ++s) fB[s] = *(const bf16x8*)(ap + 32 * KROW + s * 16);
            if (__any(tmax16(acc2) >= TmB)) {
#pragma unroll
                for (int j = 0; j < 16; ++j)
                    if (acc2[j] >= TmB) { if (cB < CAP) bufB[cB] = (unsigned short)(code0 + RJ(j)); ++cB; }
            }
        }
        ap += 64 * KROW;
    }
    cnt[(size_t)qA * NVIEW + view] = (unsigned short)(cA < CAP ? cA : CAP);
    cnt[(size_t)qB * NVIEW + view] = (unsigned short)(cB < CAP ? cB : CAP);
}

// ---- numpy pairwise_sum (n=64 base case), mul/add NOT contracted ----------
__device__ __forceinline__ float np_pairwise_sq64(const float* __restrict__ p) {
    float r[8];
#pragma unroll
    for (int j = 0; j < 8; ++j) r[j] = __fmul_rn(p[j], p[j]);
#pragma unroll
    for (int k = 1; k < 8; ++k)
#pragma unroll
        for (int j = 0; j < 8; ++j)
            r[j] = __fadd_rn(r[j], __fmul_rn(p[8 * k + j], p[8 * k + j]));
    const float t01 = __fadd_rn(r[0], r[1]);
    const float t23 = __fadd_rn(r[2], r[3]);
    const float t45 = __fadd_rn(r[4], r[5]);
    const float t67 = __fadd_rn(r[6], r[7]);
    return __fadd_rn(__fadd_rn(t01, t23), __fadd_rn(t45, t67));
}

// reference-f32 score key: ((2*xc - x2) - c2), xc = sequential fma chain
__device__ __forceinline__ float score_key(const float* __restrict__ xr,
                                           const float* __restrict__ cr,
                                           float x2e) {
    float xc = 0.f;
#pragma unroll
    for (int d = 0; d < DIM; ++d) xc = __builtin_fmaf(cr[d], xr[d], xc);
    const float c2e = np_pairwise_sq64(cr);
    return __fsub_rn(__fsub_rn(__fmul_rn(2.0f, xc), x2e), c2e);
}

// ---------------- kernel 6: exact-f32 rescore of survivors -----------------
// one wave per query; per-lane view counts -> wave prefix-sum -> LDS compact.
// ids written as FLOAT32 VALUES (harness reads whole d_out as f32).
__global__ __launch_bounds__(256) void k_rescore(const float* __restrict__ x,
                                                 const float* __restrict__ cb,
                                                 const unsigned short* __restrict__ cand,
                                                 const unsigned short* __restrict__ cnt,
                                                 float* __restrict__ out0,
                                                 float* __restrict__ out1) {
    __shared__ int s_ids[4][MAXSUR];
    const int lane = threadIdx.x & 63;
    const int wvi = threadIdx.x >> 6;
    const int q = blockIdx.x * 4 + wvi;
    const float* xr = x + ((size_t)q << 6);
    const float x2e = np_pairwise_sq64(xr);

    // lane = view; compact all survivors into LDS
    const int c = cnt[(size_t)q * NVIEW + lane];
    int p = c;
#pragma unroll
    for (int off = 1; off < 64; off <<= 1) {
        const int t = __shfl_up(p, off, 64);
        if (lane >= off) p += t;
    }
    const int excl = p - c;
    int total = __shfl(p, 63, 64);
    if (total > MAXSUR) total = MAXSUR;
    const unsigned short* src = cand + ((size_t)q * NVIEW + lane) * CAP;
    for (int k = 0; k < c; ++k) {
        const int dst = excl + k;
        if (dst < MAXSUR) s_ids[wvi][dst] = src[k];
    }
    __syncthreads();

    float vv[6]; int id[6];
#pragma unroll
    for (int s = 0; s < 6; ++s) {
        vv[s] = -FLT_MAX; id[s] = 1 << 20;
        if (s * 64 < total) {
            const int pos = lane + 64 * s;
            if (pos < total) {
                const int idv = s_ids[wvi][pos];
                id[s] = idv;
                vv[s] = score_key(xr, cb + (size_t)idv * DIM, x2e);
            }
        }
    }

    double accd = 0.0;
#pragma unroll
    for (int rep = 0; rep < KC; ++rep) {
        float bv = vv[0]; int bi = id[0];
#pragma unroll
        for (int s = 1; s < 6; ++s)
            if (vv[s] > bv || (vv[s] == bv && id[s] < bi)) { bv = vv[s]; bi = id[s]; }
#pragma unroll
        for (int off = 32; off; off >>= 1) {
            const float ov = __shfl_xor(bv, off, 64);
            const int   oi = __shfl_xor(bi, off, 64);
            if (ov > bv || (ov == bv && oi < bi)) { bv = ov; bi = oi; }
        }
        if (lane == 0) out1[q * KC + rep] = (float)bi;   // rank-ordered ids
        accd += (double)cb[(size_t)bi * DIM + lane];     // lane = dim
#pragma unroll
        for (int s = 0; s < 6; ++s) if (id[s] == bi) vv[s] = -FLT_MAX;
    }
    out0[(size_t)q * DIM + lane] = (float)(accd * 0.125);
}

// ---------------------------------------------------------------------------
extern "C" void kernel_launch(void* const* d_in, const int* in_sizes, int n_in,
                              void* d_out, int out_size, void* d_ws, size_t ws_size,
                              hipStream_t stream) {
    const float* x  = (const float*)d_in[0];   // [8192][64]
    const float* cb = (const float*)d_in[1];   // [65536][64]

    char* ws = (char*)d_ws;
    unsigned short* cbb  = (unsigned short*)ws;                                  // 10.0 MB
    unsigned short* xb   = (unsigned short*)(ws + (size_t)NCODES * KROW * 2);    // 1.25 MB (absorbs prefetch overrun)
    float*          top1 = (float*)(ws + (size_t)NCODES * KROW * 2
                                       + (size_t)NQ * KROW * 2);                 // 2 MB
    float*          thrm = (float*)((char*)top1 + (size_t)NQ * NVIEW * 4);       // 32 KB
    unsigned short* cnt  = (unsigned short*)((char*)thrm + (size_t)NQ * 4);      // 1 MB
    unsigned short* cand = (unsigned short*)((char*)cnt + (size_t)NQ * NVIEW * 2); // 12.6 MB

    float* out0 = (float*)d_out;                       // [8192][64] f32
    float* out1 = (float*)d_out + (size_t)NQ * DIM;    // [8192][8] ids-as-f32

    k_conv_cb<<<NCODES / 256, 256, 0, stream>>>(cb, cbb);
    k_conv_x <<<NQ / 256,     256, 0, stream>>>(x, xb);
    k_scanA  <<<1024,         256, 0, stream>>>(cbb, xb, top1);
    k_thresh <<<NQ / 4,       256, 0, stream>>>(top1, thrm);
    k_collect<<<1024,         256, 0, stream>>>(cbb, xb, thrm, cand, cnt);
    k_rescore<<<NQ / 4,       256, 0, stream>>>(x, cb, cand, cnt, out0, out1);
}